// Round 6
// baseline (981.360 us; speedup 1.0000x reference)
//
#include <hip/hip_runtime.h>

#define EPS_BN 1e-5f

constexpr int NN   = 20000;       // nodes
constexpr int NE   = 320000;      // edges
constexpr int NTOT = NE + NN;     // edges + self loops
constexpr int NG   = 512;         // graphs
constexpr int MPAD = 20480;       // 160 * 128 rows

typedef _Float16 half8  __attribute__((ext_vector_type(8)));
typedef _Float16 half2v __attribute__((ext_vector_type(2)));
typedef float floatx4   __attribute__((ext_vector_type(4)));

__device__ __forceinline__ void gload_lds16(const void* g, void* l) {
  __builtin_amdgcn_global_load_lds(
      (const __attribute__((address_space(1))) void*)g,
      (__attribute__((address_space(3))) void*)l, 16, 0, 0);
}

// ------------------------------------------------------------------
// Graph preprocessing
// ------------------------------------------------------------------
__global__ void k_deg(const int* __restrict__ col, int* __restrict__ deg,
                      const int* __restrict__ batch, int* __restrict__ gcnt) {
  int e = blockIdx.x * blockDim.x + threadIdx.x;
  if (e >= NTOT) return;
  int c = (e < NE) ? col[e] : (e - NE);
  atomicAdd(&deg[c], 1);
  if (e < NN) atomicAdd(&gcnt[batch[e]], 1);
}

__global__ __launch_bounds__(1024) void k_scan(const int* __restrict__ counts, int n,
                                               int* __restrict__ out_ptr,
                                               int* __restrict__ cursor,
                                               float* __restrict__ dinvv) {
  __shared__ int ssum[1024];
  int tid = threadIdx.x;
  int per = (n + 1023) / 1024;
  int beg = tid * per;
  int end = min(beg + per, n);
  int s = 0;
  for (int i = beg; i < end; ++i) {
    s += counts[i];
    if (dinvv) dinvv[i] = rsqrtf((float)counts[i]);
  }
  ssum[tid] = s;
  __syncthreads();
  for (int off = 1; off < 1024; off <<= 1) {
    int v = ssum[tid];
    int add = (tid >= off) ? ssum[tid - off] : 0;
    __syncthreads();
    ssum[tid] = v + add;
    __syncthreads();
  }
  int excl = (tid == 0) ? 0 : ssum[tid - 1];
  for (int i = beg; i < end; ++i) {
    out_ptr[i] = excl;
    cursor[i]  = excl;
    excl += counts[i];
  }
  if (tid == 1023) out_ptr[n] = ssum[1023];
}

// CSR fill with packed {src, w_bits} meta + rowsum
__global__ void k_fill(const int* __restrict__ row, const int* __restrict__ col,
                       const float* __restrict__ dinv, int* __restrict__ cursor,
                       int2* __restrict__ csw, float* __restrict__ rsum) {
  int e = blockIdx.x * blockDim.x + threadIdx.x;
  if (e >= NTOT) return;
  int r, c;
  if (e < NE) { r = row[e]; c = col[e]; } else { r = c = e - NE; }
  float wv = dinv[r] * dinv[c];
  int pos = atomicAdd(&cursor[c], 1);
  int2 m; m.x = r; m.y = __builtin_bit_cast(int, wv);
  csw[pos] = m;
  atomicAdd(&rsum[c], wv);
}

// ------------------------------------------------------------------
// Weight transposes (W1 pad 29->32, W4, W5) in one kernel
// ------------------------------------------------------------------
__global__ void k_wconv3(const float* __restrict__ W0, const float* __restrict__ W3,
                         const float* __restrict__ W4,
                         _Float16* __restrict__ T0, _Float16* __restrict__ T3,
                         _Float16* __restrict__ T4) {
  int idx = blockIdx.x * blockDim.x + threadIdx.x;
  if (idx < 32768) {                       // W1: K=29 (pad 32), N=1024
    int n = idx >> 5, k = idx & 31;
    T0[idx] = (_Float16)((k < 29) ? W0[(size_t)k * 1024 + n] : 0.f);
  } else if (idx < 32768 + 131072) {       // W4: K=256, N=512
    int j = idx - 32768;
    int n = j >> 8, k = j & 255;
    T3[j] = (_Float16)W3[(size_t)k * 512 + n];
  } else if (idx < 32768 + 131072 + 524288) { // W5: K=512, N=1024
    int j = idx - 163840;
    int n = j >> 9, k = j & 511;
    T4[j] = (_Float16)W4[(size_t)k * 1024 + n];
  }
}

// W' = diag(sc) W transposed to [N,K] fp16; c[n] = sum_k sh_k W[k,n]
__global__ __launch_bounds__(256) void k_wfold(const float* __restrict__ W, int K, int N,
                                               const float* __restrict__ sums,
                                               const float* __restrict__ gamma,
                                               const float* __restrict__ beta,
                                               _Float16* __restrict__ T,
                                               float* __restrict__ c) {
  __shared__ float red[256];
  int n = blockIdx.x, tid = threadIdx.x;
  const float inv_n = 1.f / NN;
  float csum = 0.f;
  for (int k = tid; k < K; k += 256) {
    float mean = sums[k] * inv_n;
    float var  = sums[K + k] * inv_n - mean * mean;
    float sc   = gamma[k] * rsqrtf(var + EPS_BN);
    float sh   = beta[k] - mean * sc;
    float wv   = W[(size_t)k * N + n];
    T[(size_t)n * K + k] = (_Float16)(sc * wv);
    csum += sh * wv;
  }
  red[tid] = csum;
  __syncthreads();
  for (int o = 128; o > 0; o >>= 1) {
    if (tid < o) red[tid] += red[tid + o];
    __syncthreads();
  }
  if (tid == 0) c[n] = red[0];
}

// ------------------------------------------------------------------
// L1 aggregation: fp32 x (F=29) -> fp16 out (stride 32)
// ------------------------------------------------------------------
#define AGG_T  128
#define AGG_CH 128
__global__ __launch_bounds__(AGG_T) void k_agg29(
    const float* __restrict__ X,
    const int* __restrict__ indptr, const int2* __restrict__ csw,
    _Float16* __restrict__ Y) {
  __shared__ int   s_src[AGG_CH];
  __shared__ float s_w[AGG_CH];
  int node = blockIdx.x;
  int tid  = threadIdx.x;
  int beg = indptr[node], end = indptr[node + 1];
  float acc = 0.f;
  for (int e0 = beg; e0 < end; e0 += AGG_CH) {
    int c = min(AGG_CH, end - e0);
    if (tid < c) {
      int2 m = csw[e0 + tid];
      s_src[tid] = m.x;
      s_w[tid]   = __builtin_bit_cast(float, m.y);
    }
    __syncthreads();
    for (int j = 0; j < c; ++j) {
      if (tid < 29) acc += s_w[j] * X[(size_t)s_src[j] * 29 + tid];
    }
    __syncthreads();
  }
  if (tid < 32) Y[(size_t)node * 32 + tid] = (tid < 29) ? (_Float16)acc : (_Float16)0.f;
}

// ------------------------------------------------------------------
// 64-feature-chunked scalarized gather aggregation.
// Wave per (node, 64-feat chunk); lane = feature. Chunk footprint
// 20000*128B = 2.5MB -> XCD-L2 resident. Edge meta staged in registers
// (one int2 per lane, coalesced) and broadcast via readlane under a
// scalar loop -> per edge: 2 readlane + SGPR-base ushort load + cvt + fma.
// MODE 0: out = relu(acc + s*p0[f] + p1[f])
// MODE 1: out = sc[f]*acc + s*sh[f]  (BN from sums p0, gamma p1, beta p2)
// ------------------------------------------------------------------
template<int F, int MODE>
__global__ __launch_bounds__(256) void k_aggg(
    const _Float16* __restrict__ X, _Float16* __restrict__ Y,
    const int* __restrict__ indptr, const int2* __restrict__ csw,
    const float* __restrict__ rowsum,
    const float* __restrict__ p0, const float* __restrict__ p1,
    const float* __restrict__ p2)
{
  constexpr int NB = NN / 4;                 // 5000 node-blocks per chunk
  int wave = threadIdx.x >> 6;
  int lane = threadIdx.x & 63;
  int chunk = blockIdx.x / NB;               // chunk-major: co-resident blocks share chunk
  int nb    = blockIdx.x - chunk * NB;
  int node  = nb * 4 + wave;
  int fbase = chunk * 64;
  int f     = fbase + lane;

  int beg = __builtin_amdgcn_readfirstlane(indptr[node]);
  int end = __builtin_amdgcn_readfirstlane(indptr[node + 1]);

  const _Float16* Xc = X + fbase;            // uniform base; +lane is the voffset
  float acc = 0.f;

  for (int t = beg; t < end; t += 64) {
    int idx = t + lane;
    if (idx >= end) idx = end - 1;           // clamp (dup loads unused)
    int2 m = csw[idx];
    int sv = m.x;
    int wv = m.y;
    int cnt = min(64, end - t);
    for (int j = 0; j < cnt; ++j) {
      int   sj = __builtin_amdgcn_readlane(sv, j);
      float wj = __builtin_bit_cast(float, __builtin_amdgcn_readlane(wv, j));
      _Float16 xv = Xc[(size_t)sj * F + lane];
      acc = fmaf(wj, (float)xv, acc);
    }
  }

  float s_n = rowsum[node];
  float v;
  if constexpr (MODE == 0) {
    v = fmaxf(acc + s_n * p0[f] + p1[f], 0.f);
  } else {
    const float inv_n = 1.f / NN;
    float mean = p0[f] * inv_n;
    float var  = p0[F + f] * inv_n - mean * mean;
    float sc   = p1[f] * rsqrtf(var + EPS_BN);
    float sh   = p2[f] - mean * sc;
    v = sc * acc + s_n * sh;
  }
  Y[(size_t)node * F + f] = (_Float16)v;
}

// ------------------------------------------------------------------
// fp16 MFMA GEMM, 128x128 tile, XCD-swizzled grid, XOR-swizzled LDS.
// ------------------------------------------------------------------
template<int BK>
__global__ __launch_bounds__(256) void k_gemm16(
    const _Float16* __restrict__ A, const _Float16* __restrict__ B,
    const float* __restrict__ bias,
    float* __restrict__ Cf, _Float16* __restrict__ Ch,
    float* __restrict__ stats,
    int N, int K, int do_relu, int nbx)
{
  __shared__ __align__(16) _Float16 sA[128 * BK];
  __shared__ __align__(16) _Float16 sB[128 * BK];
  __shared__ float sred[256];

  const int tid  = threadIdx.x;
  const int wave = tid >> 6;
  const int lane = tid & 63;

  int lin = blockIdx.x;
  int xcd = lin & 7, seq = lin >> 3;
  int bx = seq % nbx, grp = seq / nbx;
  int by = xcd + 8 * grp;            // 0..159
  const int row0 = by * 128;
  const int col0 = bx * 128;

  const int q  = lane >> 4;
  const int mm = lane & 15;
  const int wm = wave >> 1;
  const int wn = wave & 1;

  sred[tid] = 0.f;

  constexpr int NREP = (BK == 32) ? 2 : 4;
  constexpr int RPW  = (BK == 32) ? 16 : 8;
  const _Float16* pA[NREP];
  const _Float16* pB[NREP];
  _Float16* dstA[NREP];
  _Float16* dstB[NREP];
  {
    int rl = (BK == 32) ? (lane >> 2) : (lane >> 3);
    int cp = (BK == 32) ? (lane & 3) : (lane & 7);
    #pragma unroll
    for (int rep = 0; rep < NREP; ++rep) {
      int trow = wave * 32 + rep * RPW;
      int s = (BK == 32) ? ((lane >> 3) & 3) : ((rep & 1) * 4 + (rl >> 1));
      int csrc = cp ^ s;
      pA[rep] = A + (size_t)(row0 + trow + rl) * K + csrc * 8;
      pB[rep] = B + (size_t)(col0 + trow + rl) * K + csrc * 8;
      dstA[rep] = sA + trow * BK;
      dstB[rep] = sB + trow * BK;
    }
  }

  const int sR = (BK == 32) ? ((mm >> 1) & 3) : (mm >> 1);
  const _Float16* rdA[4];
  const _Float16* rdB[4];
  #pragma unroll
  for (int i = 0; i < 4; ++i) {
    rdA[i] = &sA[(wm * 64 + i * 16 + mm) * BK];
    rdB[i] = &sB[(wn * 64 + i * 16 + mm) * BK];
  }

  floatx4 acc[4][4];
  #pragma unroll
  for (int i = 0; i < 4; ++i)
    #pragma unroll
    for (int j = 0; j < 4; ++j) acc[i][j] = floatx4{0.f, 0.f, 0.f, 0.f};

  for (int k0 = 0; k0 < K; k0 += BK) {
    #pragma unroll
    for (int rep = 0; rep < NREP; ++rep) {
      gload_lds16(pA[rep], dstA[rep]);
      gload_lds16(pB[rep], dstB[rep]);
      pA[rep] += BK; pB[rep] += BK;
    }
    __syncthreads();

    #pragma unroll
    for (int kk = 0; kk < BK / 32; ++kk) {
      int pos = ((q + 4 * kk) ^ sR) * 8;
      half8 av[4];
      #pragma unroll
      for (int i = 0; i < 4; ++i) av[i] = *(const half8*)(rdA[i] + pos);
      #pragma unroll
      for (int j = 0; j < 4; ++j) {
        half8 bv = *(const half8*)(rdB[j] + pos);
        #pragma unroll
        for (int i = 0; i < 4; ++i)
          acc[i][j] = __builtin_amdgcn_mfma_f32_16x16x32_f16(av[i], bv, acc[i][j], 0, 0, 0);
      }
    }
    __syncthreads();
  }

  float sloc[4]  = {0.f, 0.f, 0.f, 0.f};
  float s2loc[4] = {0.f, 0.f, 0.f, 0.f};
  #pragma unroll
  for (int j = 0; j < 4; ++j) {
    int cc = col0 + wn * 64 + j * 16 + mm;
    float bv = bias ? bias[cc] : 0.f;
    #pragma unroll
    for (int i = 0; i < 4; ++i) {
      #pragma unroll
      for (int r = 0; r < 4; ++r) {
        int rr = row0 + wm * 64 + i * 16 + q * 4 + r;
        if (rr < NN) {
          float v = acc[i][j][r] + bv;
          if (do_relu) v = fmaxf(v, 0.f);
          if (Cf) Cf[(size_t)rr * N + cc] = v;
          else    Ch[(size_t)rr * N + cc] = (_Float16)v;
          sloc[j]  += v;
          s2loc[j] += v * v;
        }
      }
    }
  }

  if (stats) {
    #pragma unroll
    for (int j = 0; j < 4; ++j) {
      float a = sloc[j], b2 = s2loc[j];
      a  += __shfl_xor(a, 16, 64);  a  += __shfl_xor(a, 32, 64);
      b2 += __shfl_xor(b2, 16, 64); b2 += __shfl_xor(b2, 32, 64);
      if (q == 0) {
        int cl = wn * 64 + j * 16 + mm;
        atomicAdd(&sred[cl], a);
        atomicAdd(&sred[128 + cl], b2);
      }
    }
    __syncthreads();
    if (tid < 128) {
      atomicAdd(&stats[col0 + tid], sred[tid]);
      atomicAdd(&stats[N + col0 + tid], sred[128 + tid]);
    }
  }
}

// ------------------------------------------------------------------
// Slim BN stats over fp16 tensor (stride == F)
// ------------------------------------------------------------------
__global__ __launch_bounds__(256) void k_stats16(const _Float16* __restrict__ X, int F,
                                                 float* __restrict__ sums) {
  int tid = threadIdx.x;
  int npf = F >> 8;
  float s[2] = {0.f, 0.f}, s2[2] = {0.f, 0.f};
  for (int r = blockIdx.x; r < NN; r += gridDim.x) {
    #pragma unroll
    for (int i = 0; i < 2; ++i) {
      if (i < npf) {
        float v = (float)X[(size_t)r * F + tid + i * 256];
        s[i] += v; s2[i] += v * v;
      }
    }
  }
  #pragma unroll
  for (int i = 0; i < 2; ++i) {
    if (i < npf) {
      atomicAdd(&sums[tid + i * 256], s[i]);
      atomicAdd(&sums[F + tid + i * 256], s2[i]);
    }
  }
}

// ------------------------------------------------------------------
// L5 BN fold for pooling
// ------------------------------------------------------------------
__global__ __launch_bounds__(1024) void k_prep(const float* __restrict__ sums,
                                               const float* __restrict__ g5,
                                               const float* __restrict__ be5,
                                               const float* __restrict__ Wg,
                                               const float* __restrict__ bg,
                                               float* __restrict__ sc, float* __restrict__ sh,
                                               float* __restrict__ scWg, float* __restrict__ gconst) {
  __shared__ float red[1024];
  int f = threadIdx.x;
  const float inv_n = 1.f / NN;
  float mean = sums[f] * inv_n;
  float var  = sums[1024 + f] * inv_n - mean * mean;
  float s = g5[f] * rsqrtf(var + EPS_BN);
  float h = be5[f] - mean * s;
  sc[f] = s; sh[f] = h;
  float wgf = Wg[f];
  scWg[f] = s * wgf;
  red[f] = h * wgf;
  __syncthreads();
  for (int o = 512; o > 0; o >>= 1) {
    if (f < o) red[f] += red[f + o];
    __syncthreads();
  }
  if (f == 0) gconst[0] = red[0] + bg[0];
}

__global__ __launch_bounds__(256) void k_gate_aff(const _Float16* __restrict__ X,
                                                  const float* __restrict__ scWg,
                                                  const float* __restrict__ gconst,
                                                  float* __restrict__ gate) {
  __shared__ float red[256];
  int n = blockIdx.x, tid = threadIdx.x;
  int f = tid * 4;
  uint2 u = *(const uint2*)(X + (size_t)n * 1024 + f);
  half2v h0 = __builtin_bit_cast(half2v, u.x);
  half2v h1 = __builtin_bit_cast(half2v, u.y);
  float s = (float)h0[0] * scWg[f] + (float)h0[1] * scWg[f + 1]
          + (float)h1[0] * scWg[f + 2] + (float)h1[1] * scWg[f + 3];
  red[tid] = s;
  __syncthreads();
  for (int o = 128; o > 0; o >>= 1) {
    if (tid < o) red[tid] += red[tid + o];
    __syncthreads();
  }
  if (tid == 0) gate[n] = red[0] + gconst[0];
}

__global__ __launch_bounds__(64) void k_segred(const float* __restrict__ gate,
                                               const int* __restrict__ goff,
                                               float* __restrict__ gmax,
                                               float* __restrict__ gsum) {
  int g = blockIdx.x, tid = threadIdx.x;
  int beg = goff[g], end = goff[g + 1];
  float m = -3.4e38f;
  for (int n = beg + tid; n < end; n += 64) m = fmaxf(m, gate[n]);
  for (int o = 32; o > 0; o >>= 1) m = fmaxf(m, __shfl_down(m, o, 64));
  m = __shfl(m, 0, 64);
  float s = 0.f;
  for (int n = beg + tid; n < end; n += 64) s += expf(gate[n] - m);
  for (int o = 32; o > 0; o >>= 1) s += __shfl_down(s, o, 64);
  if (tid == 0) { gmax[g] = m; gsum[g] = s; }
}

__global__ __launch_bounds__(256) void k_pool_aff(const _Float16* __restrict__ X,
                                                  const float* __restrict__ gate,
                                                  const int* __restrict__ goff,
                                                  const float* __restrict__ gmax,
                                                  const float* __restrict__ gsum,
                                                  const float* __restrict__ sc,
                                                  const float* __restrict__ sh,
                                                  float* __restrict__ pooled) {
  int g = blockIdx.x, tid = threadIdx.x;
  int beg = goff[g], end = goff[g + 1];
  int f = tid * 4;
  float acc[4] = {0.f, 0.f, 0.f, 0.f};
  bool nonempty = end > beg;
  if (nonempty) {
    float m = gmax[g], inv = 1.f / gsum[g];
    for (int n = beg; n < end; ++n) {
      float a = expf(gate[n] - m) * inv;
      uint2 u = *(const uint2*)(X + (size_t)n * 1024 + f);
      half2v h0 = __builtin_bit_cast(half2v, u.x);
      half2v h1 = __builtin_bit_cast(half2v, u.y);
      acc[0] += a * (float)h0[0];
      acc[1] += a * (float)h0[1];
      acc[2] += a * (float)h1[0];
      acc[3] += a * (float)h1[1];
    }
  }
  #pragma unroll
  for (int i = 0; i < 4; ++i) {
    int ff = f + i;
    float v = nonempty ? (acc[i] * sc[ff] + sh[ff]) : 0.f;
    pooled[(size_t)g * 1024 + ff] = v;
  }
}

// ------------------------------------------------------------------
// MLP head
// ------------------------------------------------------------------
__global__ __launch_bounds__(128) void k_head(const float* __restrict__ pooled,
                                              const float* __restrict__ Wf2, const float* __restrict__ bf2,
                                              const float* __restrict__ Wf3, const float* __restrict__ bf3,
                                              const float* __restrict__ Wf4, const float* __restrict__ bf4,
                                              float* __restrict__ out) {
  __shared__ float sp[1024];
  __shared__ float sp2[128];
  __shared__ float sp3[16];
  int g = blockIdx.x, tid = threadIdx.x;
  #pragma unroll
  for (int i = 0; i < 8; ++i) sp[tid + i * 128] = pooled[(size_t)g * 1024 + tid + i * 128];
  __syncthreads();
  float s = bf2[tid];
  for (int k = 0; k < 1024; ++k) s += sp[k] * Wf2[k * 128 + tid];
  sp2[tid] = fmaxf(s, 0.f);
  __syncthreads();
  if (tid < 16) {
    float t = bf3[tid];
    for (int k = 0; k < 128; ++k) t += sp2[k] * Wf3[k * 16 + tid];
    sp3[tid] = fmaxf(t, 0.f);
  }
  __syncthreads();
  if (tid == 0) {
    float t = bf4[0];
    for (int k = 0; k < 16; ++k) t += sp3[k] * Wf4[k];
    out[g] = t;
  }
}

// ------------------------------------------------------------------
extern "C" void kernel_launch(void* const* d_in, const int* in_sizes, int n_in,
                              void* d_out, int out_size, void* d_ws, size_t ws_size,
                              hipStream_t stream) {
  const float* x     = (const float*)d_in[0];
  const int*   ei    = (const int*)d_in[1];
  const int*   batch = (const int*)d_in[2];
  const float* W[5]; const float* b[5]; const float* g[5]; const float* be[5];
  for (int l = 0; l < 5; ++l) {
    W[l]  = (const float*)d_in[3 + 4 * l];
    b[l]  = (const float*)d_in[4 + 4 * l];
    g[l]  = (const float*)d_in[5 + 4 * l];
    be[l] = (const float*)d_in[6 + 4 * l];
  }
  const float* Wg  = (const float*)d_in[23];
  const float* bg  = (const float*)d_in[24];
  const float* Wf2 = (const float*)d_in[25];
  const float* bf2 = (const float*)d_in[26];
  const float* Wf3 = (const float*)d_in[27];
  const float* bf3 = (const float*)d_in[28];
  const float* Wf4 = (const float*)d_in[29];
  const float* bf4 = (const float*)d_in[30];
  float* out = (float*)d_out;

  const int* row = ei;
  const int* col = ei + NE;

  char* base = (char*)d_ws;
  size_t off = 0;
  auto alloc = [&](size_t bytes) -> char* {
    char* p = base + off;
    off = (off + bytes + 255) & ~(size_t)255;
    return p;
  };
  _Float16*  AH  = (_Float16*)alloc((size_t)MPAD * 1024 * 2); // GEMM A operand / r2 / a4 / a5
  _Float16*  ASM = (_Float16*)alloc((size_t)MPAD * 32 * 2);   // L1 A operand
  _Float16*  BF  = (_Float16*)alloc((size_t)NN * 512 * 2);    // gather buffer
  _Float16*  BF2 = (_Float16*)alloc((size_t)NN * 512 * 2);    // gather buffer
  _Float16*  H5  = (_Float16*)alloc((size_t)NN * 1024 * 2);   // r5 fp16
  const int wtsz[5] = {1024 * 32, 512 * 1024, 256 * 512, 512 * 256, 1024 * 512};
  _Float16* WT[5];
  for (int l = 0; l < 5; ++l) WT[l] = (_Float16*)alloc((size_t)wtsz[l] * 2);
  float* c2  = (float*)alloc(512 * 4);
  float* c3  = (float*)alloc(256 * 4);
  float* dinv    = (float*)alloc(NN * 4);
  int*   indptr  = (int*)alloc((NN + 1) * 4);
  int*   cursor  = (int*)alloc(NN * 4);
  int2*  csw     = (int2*)alloc((size_t)NTOT * 8);
  int*   goff    = (int*)alloc((NG + 1) * 4);
  int*   gcur    = (int*)alloc(NG * 4);
  float* gate    = (float*)alloc(NN * 4);
  float* gmax    = (float*)alloc(NG * 4);
  float* gsum    = (float*)alloc(NG * 4);
  float* pooled  = (float*)alloc((size_t)NG * 1024 * 4);
  float* scv5 = (float*)alloc(1024 * 4);
  float* shv5 = (float*)alloc(1024 * 4);
  float* scWg = (float*)alloc(1024 * 4);
  float* gconst = (float*)alloc(4);
  // single zeroed region: bns(6656) | deg(NN) | gcnt(NG) | rsum(NN)
  size_t znf = 6656 + NN + NG + NN;
  float* zbase = (float*)alloc(znf * 4);
  float* bns  = zbase;
  int*   deg  = (int*)(zbase + 6656);
  int*   gcnt = (int*)(zbase + 6656 + NN);
  float* rsum = zbase + 6656 + NN + NG;
  float* bns1 = bns;          // F=1024
  float* bns2 = bns + 2048;   // F=512
  float* bns3 = bns + 3072;   // F=256
  float* bns4 = bns + 3584;   // F=512
  float* bns5 = bns + 4608;   // F=1024

  // ---- preprocessing ----
  hipMemsetAsync(zbase, 0, znf * 4, stream);
  k_deg<<<(NTOT + 255) / 256, 256, 0, stream>>>(col, deg, batch, gcnt);
  k_scan<<<1, 1024, 0, stream>>>(deg, NN, indptr, cursor, dinv);
  k_fill<<<(NTOT + 255) / 256, 256, 0, stream>>>(row, col, dinv, cursor, csw, rsum);
  k_scan<<<1, 1024, 0, stream>>>(gcnt, NG, goff, gcur, nullptr);
  k_wconv3<<<2688, 256, 0, stream>>>(W[0], W[3], W[4], WT[0], WT[3], WT[4]);

  auto gemm = [&](const _Float16* Aop, int wl, const float* bias,
                  float* Cf, _Float16* Ch, float* stats, int Nn, int Kk, int relu) {
    int nbx = Nn / 128;
    if (Kk == 32)
      k_gemm16<32><<<nbx * 160, 256, 0, stream>>>(Aop, WT[wl], bias, Cf, Ch, stats, Nn, Kk, relu, nbx);
    else
      k_gemm16<64><<<nbx * 160, 256, 0, stream>>>(Aop, WT[wl], bias, Cf, Ch, stats, Nn, Kk, relu, nbx);
  };

  // ---- layer 1 (29 -> 1024): agg-first; GEMM1 fuses bias/relu/stats ----
  k_agg29<<<NN, AGG_T, 0, stream>>>(x, indptr, csw, ASM);
  gemm(ASM, 0, b[0], nullptr, AH, bns1, 1024, 32, 1);            // r1 fp16

  // ---- layer 2 (1024 -> 512): BN1 folded into W2; transform-first ----
  k_wfold<<<512, 256, 0, stream>>>(W[1], 1024, 512, bns1, g[0], be[0], WT[1], c2);
  gemm(AH, 1, nullptr, nullptr, BF, nullptr, 512, 1024, 0);      // G2
  k_aggg<512, 0><<<5000 * 8, 256, 0, stream>>>(BF, AH, indptr, csw, rsum, c2, b[1], nullptr); // r2
  k_stats16<<<512, 256, 0, stream>>>(AH, 512, bns2);

  // ---- layer 3 (512 -> 256): BN2 folded into W3; transform-first ----
  k_wfold<<<256, 256, 0, stream>>>(W[2], 512, 256, bns2, g[1], be[1], WT[2], c3);
  gemm(AH, 2, nullptr, nullptr, BF2, nullptr, 256, 512, 0);      // G3
  k_aggg<256, 0><<<5000 * 4, 256, 0, stream>>>(BF2, BF, indptr, csw, rsum, c3, b[2], nullptr); // r3
  k_stats16<<<512, 256, 0, stream>>>(BF, 256, bns3);

  // ---- layer 4 (256 -> 512): agg-first, BN3 inline in agg epilogue ----
  k_aggg<256, 1><<<5000 * 4, 256, 0, stream>>>(BF, AH, indptr, csw, rsum, bns3, g[2], be[2]); // a4
  gemm(AH, 3, b[3], nullptr, BF2, bns4, 512, 256, 1);            // r4 fp16 + stats

  // ---- layer 5 (512 -> 1024): agg-first, BN4 inline; GEMM5 fp16 out ----
  k_aggg<512, 1><<<5000 * 8, 256, 0, stream>>>(BF2, AH, indptr, csw, rsum, bns4, g[3], be[3]); // a5
  gemm(AH, 4, b[4], nullptr, H5, bns5, 1024, 512, 1);            // r5 fp16 + stats

  // ---- attention pooling with folded BN5 affine ----
  k_prep<<<1, 1024, 0, stream>>>(bns5, g[4], be[4], Wg, bg, scv5, shv5, scWg, gconst);
  k_gate_aff<<<NN, 256, 0, stream>>>(H5, scWg, gconst, gate);
  k_segred<<<NG, 64, 0, stream>>>(gate, goff, gmax, gsum);
  k_pool_aff<<<NG, 256, 0, stream>>>(H5, gate, goff, gmax, gsum, scv5, shv5, pooled);

  // ---- MLP head ----
  k_head<<<NG, 128, 0, stream>>>(pooled, Wf2, bf2, Wf3, bf3, Wf4, bf4, out);
}

// Round 7
// 693.032 us; speedup vs baseline: 1.4160x; 1.4160x over previous
//
#include <hip/hip_runtime.h>

#define EPS_BN 1e-5f

constexpr int NN   = 20000;       // nodes
constexpr int NE   = 320000;      // edges
constexpr int NTOT = NE + NN;     // edges + self loops
constexpr int NG   = 512;         // graphs
constexpr int MPAD = 20480;       // 160 * 128 rows

typedef _Float16 half8  __attribute__((ext_vector_type(8)));
typedef _Float16 half2v __attribute__((ext_vector_type(2)));
typedef float floatx4   __attribute__((ext_vector_type(4)));

__device__ __forceinline__ void gload_lds16(const void* g, void* l) {
  __builtin_amdgcn_global_load_lds(
      (const __attribute__((address_space(1))) void*)g,
      (__attribute__((address_space(3))) void*)l, 16, 0, 0);
}

// ------------------------------------------------------------------
// Graph preprocessing
// ------------------------------------------------------------------
__global__ void k_deg(const int* __restrict__ col, int* __restrict__ deg,
                      const int* __restrict__ batch, int* __restrict__ gcnt) {
  int e = blockIdx.x * blockDim.x + threadIdx.x;
  if (e >= NTOT) return;
  int c = (e < NE) ? col[e] : (e - NE);
  atomicAdd(&deg[c], 1);
  if (e < NN) atomicAdd(&gcnt[batch[e]], 1);
}

__global__ __launch_bounds__(1024) void k_scan(const int* __restrict__ counts, int n,
                                               int* __restrict__ out_ptr,
                                               int* __restrict__ cursor,
                                               float* __restrict__ dinvv) {
  __shared__ int ssum[1024];
  int tid = threadIdx.x;
  int per = (n + 1023) / 1024;
  int beg = tid * per;
  int end = min(beg + per, n);
  int s = 0;
  for (int i = beg; i < end; ++i) {
    s += counts[i];
    if (dinvv) dinvv[i] = rsqrtf((float)counts[i]);
  }
  ssum[tid] = s;
  __syncthreads();
  for (int off = 1; off < 1024; off <<= 1) {
    int v = ssum[tid];
    int add = (tid >= off) ? ssum[tid - off] : 0;
    __syncthreads();
    ssum[tid] = v + add;
    __syncthreads();
  }
  int excl = (tid == 0) ? 0 : ssum[tid - 1];
  for (int i = beg; i < end; ++i) {
    out_ptr[i] = excl;
    cursor[i]  = excl;
    excl += counts[i];
  }
  if (tid == 1023) out_ptr[n] = ssum[1023];
}

// CSR fill with packed {src, w_bits} meta + rowsum
__global__ void k_fill(const int* __restrict__ row, const int* __restrict__ col,
                       const float* __restrict__ dinv, int* __restrict__ cursor,
                       int2* __restrict__ csw, float* __restrict__ rsum) {
  int e = blockIdx.x * blockDim.x + threadIdx.x;
  if (e >= NTOT) return;
  int r, c;
  if (e < NE) { r = row[e]; c = col[e]; } else { r = c = e - NE; }
  float wv = dinv[r] * dinv[c];
  int pos = atomicAdd(&cursor[c], 1);
  int2 m; m.x = r; m.y = __builtin_bit_cast(int, wv);
  csw[pos] = m;
  atomicAdd(&rsum[c], wv);
}

// ------------------------------------------------------------------
// Weight transposes (W1 pad 29->32, W4, W5) in one kernel
// ------------------------------------------------------------------
__global__ void k_wconv3(const float* __restrict__ W0, const float* __restrict__ W3,
                         const float* __restrict__ W4,
                         _Float16* __restrict__ T0, _Float16* __restrict__ T3,
                         _Float16* __restrict__ T4) {
  int idx = blockIdx.x * blockDim.x + threadIdx.x;
  if (idx < 32768) {                       // W1: K=29 (pad 32), N=1024
    int n = idx >> 5, k = idx & 31;
    T0[idx] = (_Float16)((k < 29) ? W0[(size_t)k * 1024 + n] : 0.f);
  } else if (idx < 32768 + 131072) {       // W4: K=256, N=512
    int j = idx - 32768;
    int n = j >> 8, k = j & 255;
    T3[j] = (_Float16)W3[(size_t)k * 512 + n];
  } else if (idx < 32768 + 131072 + 524288) { // W5: K=512, N=1024
    int j = idx - 163840;
    int n = j >> 9, k = j & 511;
    T4[j] = (_Float16)W4[(size_t)k * 1024 + n];
  }
}

// W' = diag(sc) W transposed to [N,K] fp16; c[n] = sum_k sh_k W[k,n]
__global__ __launch_bounds__(256) void k_wfold(const float* __restrict__ W, int K, int N,
                                               const float* __restrict__ sums,
                                               const float* __restrict__ gamma,
                                               const float* __restrict__ beta,
                                               _Float16* __restrict__ T,
                                               float* __restrict__ c) {
  __shared__ float red[256];
  int n = blockIdx.x, tid = threadIdx.x;
  const float inv_n = 1.f / NN;
  float csum = 0.f;
  for (int k = tid; k < K; k += 256) {
    float mean = sums[k] * inv_n;
    float var  = sums[K + k] * inv_n - mean * mean;
    float sc   = gamma[k] * rsqrtf(var + EPS_BN);
    float sh   = beta[k] - mean * sc;
    float wv   = W[(size_t)k * N + n];
    T[(size_t)n * K + k] = (_Float16)(sc * wv);
    csum += sh * wv;
  }
  red[tid] = csum;
  __syncthreads();
  for (int o = 128; o > 0; o >>= 1) {
    if (tid < o) red[tid] += red[tid + o];
    __syncthreads();
  }
  if (tid == 0) c[n] = red[0];
}

// ------------------------------------------------------------------
// L1 aggregation: fp32 x (F=29) -> fp16 out (stride 32)
// ------------------------------------------------------------------
#define AGG_T  128
#define AGG_CH 128
__global__ __launch_bounds__(AGG_T) void k_agg29(
    const float* __restrict__ X,
    const int* __restrict__ indptr, const int2* __restrict__ csw,
    _Float16* __restrict__ Y) {
  __shared__ int   s_src[AGG_CH];
  __shared__ float s_w[AGG_CH];
  int node = blockIdx.x;
  int tid  = threadIdx.x;
  int beg = indptr[node], end = indptr[node + 1];
  float acc = 0.f;
  for (int e0 = beg; e0 < end; e0 += AGG_CH) {
    int c = min(AGG_CH, end - e0);
    if (tid < c) {
      int2 m = csw[e0 + tid];
      s_src[tid] = m.x;
      s_w[tid]   = __builtin_bit_cast(float, m.y);
    }
    __syncthreads();
    for (int j = 0; j < c; ++j) {
      if (tid < 29) acc += s_w[j] * X[(size_t)s_src[j] * 29 + tid];
    }
    __syncthreads();
  }
  if (tid < 32) Y[(size_t)node * 32 + tid] = (tid < 29) ? (_Float16)acc : (_Float16)0.f;
}

// ------------------------------------------------------------------
// Whole-row fp16 gather aggregation, wave-per-node (4 nodes/block).
// F = 64*VEC. Packed int2 edge meta (1 load), uint4/uint2 row loads,
// unroll-4 for memory parallelism. Vector fp16 output store.
// MODE 0: out = relu(acc + s*p0[f] + p1[f])
// MODE 1: out = sc[f]*acc + s*sh[f]  (BN from sums p0, gamma p1, beta p2)
// ------------------------------------------------------------------
template<int VEC, int MODE>
__global__ __launch_bounds__(256) void k_aggv(
    const _Float16* __restrict__ X, _Float16* __restrict__ Y,
    const int* __restrict__ indptr, const int2* __restrict__ csw,
    const float* __restrict__ rowsum,
    const float* __restrict__ p0, const float* __restrict__ p1,
    const float* __restrict__ p2)
{
  constexpr int F = 64 * VEC;
  int wave = threadIdx.x >> 6;
  int lane = threadIdx.x & 63;
  int node = blockIdx.x * 4 + wave;
  int beg = indptr[node], end = indptr[node + 1];
  float acc[VEC];
  #pragma unroll
  for (int i = 0; i < VEC; ++i) acc[i] = 0.f;
  const unsigned* Xl = (const unsigned*)X + lane * (VEC / 2);

  auto body = [&](int e) {
    int2 m = csw[e];
    float we = __builtin_bit_cast(float, m.y);
    const unsigned* xr = Xl + (size_t)m.x * (F / 2);
    unsigned uu[VEC / 2];
    if constexpr (VEC == 8) {
      uint4 d = *(const uint4*)xr;
      uu[0] = d.x; uu[1] = d.y; uu[2] = d.z; uu[3] = d.w;
    } else {
      uint2 d = *(const uint2*)xr;
      uu[0] = d.x; uu[1] = d.y;
    }
    #pragma unroll
    for (int i = 0; i < VEC / 2; ++i) {
      half2v h = __builtin_bit_cast(half2v, uu[i]);
      acc[2 * i]     = fmaf(we, (float)h[0], acc[2 * i]);
      acc[2 * i + 1] = fmaf(we, (float)h[1], acc[2 * i + 1]);
    }
  };
  int e = beg;
  for (; e + 4 <= end; e += 4) { body(e); body(e + 1); body(e + 2); body(e + 3); }
  for (; e < end; ++e) body(e);

  float s_n = rowsum[node];
  size_t ob = (size_t)node * F + lane * VEC;
  _Float16 outv[VEC];
  #pragma unroll
  for (int i = 0; i < VEC; ++i) {
    int f = lane * VEC + i;
    float v;
    if constexpr (MODE == 0) {
      v = fmaxf(acc[i] + s_n * p0[f] + p1[f], 0.f);
    } else {
      const float inv_n = 1.f / NN;
      float mean = p0[f] * inv_n;
      float var  = p0[F + f] * inv_n - mean * mean;
      float sc   = p1[f] * rsqrtf(var + EPS_BN);
      float sh   = p2[f] - mean * sc;
      v = sc * acc[i] + s_n * sh;
    }
    outv[i] = (_Float16)v;
  }
  if constexpr (VEC == 8) *(uint4*)(Y + ob) = *(const uint4*)outv;
  else                    *(uint2*)(Y + ob) = *(const uint2*)outv;
}

// ------------------------------------------------------------------
// fp16 MFMA GEMM, 128x128 tile, XCD-swizzled grid, XOR-swizzled LDS,
// LDS-coalesced fp16 epilogue (kills 2B-store write amplification).
// A: [MPAD,K] fp16. B^T: [N,K] fp16. Out fp16 Ch; fused bias/relu +
// optional BN stats (rows < NN only).
// ------------------------------------------------------------------
template<int BK>
__global__ __launch_bounds__(256) void k_gemm16(
    const _Float16* __restrict__ A, const _Float16* __restrict__ B,
    const float* __restrict__ bias,
    _Float16* __restrict__ Ch,
    float* __restrict__ stats,
    int N, int K, int do_relu, int nbx)
{
  __shared__ __align__(16) union UU {
    struct { _Float16 a[128 * BK]; _Float16 b[128 * BK]; } ab;
    _Float16 c[128 * 136];          // 136-elem padded rows (16B-aligned)
  } u;
  __shared__ float sred[256];

  const int tid  = threadIdx.x;
  const int wave = tid >> 6;
  const int lane = tid & 63;

  int lin = blockIdx.x;
  int xcd = lin & 7, seq = lin >> 3;
  int bx = seq % nbx, grp = seq / nbx;
  int by = xcd + 8 * grp;            // 0..159
  const int row0 = by * 128;
  const int col0 = bx * 128;

  const int q  = lane >> 4;
  const int mm = lane & 15;
  const int wm = wave >> 1;
  const int wn = wave & 1;

  sred[tid] = 0.f;

  constexpr int NREP = (BK == 32) ? 2 : 4;
  constexpr int RPW  = (BK == 32) ? 16 : 8;
  const _Float16* pA[NREP];
  const _Float16* pB[NREP];
  _Float16* dstA[NREP];
  _Float16* dstB[NREP];
  {
    int rl = (BK == 32) ? (lane >> 2) : (lane >> 3);
    int cp = (BK == 32) ? (lane & 3) : (lane & 7);
    #pragma unroll
    for (int rep = 0; rep < NREP; ++rep) {
      int trow = wave * 32 + rep * RPW;
      int s = (BK == 32) ? ((lane >> 3) & 3) : ((rep & 1) * 4 + (rl >> 1));
      int csrc = cp ^ s;
      pA[rep] = A + (size_t)(row0 + trow + rl) * K + csrc * 8;
      pB[rep] = B + (size_t)(col0 + trow + rl) * K + csrc * 8;
      dstA[rep] = u.ab.a + trow * BK;
      dstB[rep] = u.ab.b + trow * BK;
    }
  }

  const int sR = (BK == 32) ? ((mm >> 1) & 3) : (mm >> 1);
  int rdA[4], rdB[4];
  #pragma unroll
  for (int i = 0; i < 4; ++i) {
    rdA[i] = (wm * 64 + i * 16 + mm) * BK;
    rdB[i] = (wn * 64 + i * 16 + mm) * BK;
  }

  floatx4 acc[4][4];
  #pragma unroll
  for (int i = 0; i < 4; ++i)
    #pragma unroll
    for (int j = 0; j < 4; ++j) acc[i][j] = floatx4{0.f, 0.f, 0.f, 0.f};

  for (int k0 = 0; k0 < K; k0 += BK) {
    #pragma unroll
    for (int rep = 0; rep < NREP; ++rep) {
      gload_lds16(pA[rep], dstA[rep]);
      gload_lds16(pB[rep], dstB[rep]);
      pA[rep] += BK; pB[rep] += BK;
    }
    __syncthreads();

    #pragma unroll
    for (int kk = 0; kk < BK / 32; ++kk) {
      int pos = ((q + 4 * kk) ^ sR) * 8;
      half8 av[4];
      #pragma unroll
      for (int i = 0; i < 4; ++i) av[i] = *(const half8*)&u.ab.a[rdA[i] + pos];
      #pragma unroll
      for (int j = 0; j < 4; ++j) {
        half8 bv = *(const half8*)&u.ab.b[rdB[j] + pos];
        #pragma unroll
        for (int i = 0; i < 4; ++i)
          acc[i][j] = __builtin_amdgcn_mfma_f32_16x16x32_f16(av[i], bv, acc[i][j], 0, 0, 0);
      }
    }
    __syncthreads();
  }

  // epilogue: fragments -> LDS tile (+stats), then coalesced stores
  float sloc[4]  = {0.f, 0.f, 0.f, 0.f};
  float s2loc[4] = {0.f, 0.f, 0.f, 0.f};
  #pragma unroll
  for (int j = 0; j < 4; ++j) {
    int cl = wn * 64 + j * 16 + mm;
    float bv = bias ? bias[col0 + cl] : 0.f;
    #pragma unroll
    for (int i = 0; i < 4; ++i) {
      #pragma unroll
      for (int r = 0; r < 4; ++r) {
        int rl = wm * 64 + i * 16 + q * 4 + r;
        float v = acc[i][j][r] + bv;
        if (do_relu) v = fmaxf(v, 0.f);
        u.c[rl * 136 + cl] = (_Float16)v;
        if (row0 + rl < NN) { sloc[j] += v; s2loc[j] += v * v; }
      }
    }
  }

  if (stats) {
    #pragma unroll
    for (int j = 0; j < 4; ++j) {
      float a = sloc[j], b2 = s2loc[j];
      a  += __shfl_xor(a, 16, 64);  a  += __shfl_xor(a, 32, 64);
      b2 += __shfl_xor(b2, 16, 64); b2 += __shfl_xor(b2, 32, 64);
      if (q == 0) {
        int cl = wn * 64 + j * 16 + mm;
        atomicAdd(&sred[cl], a);
        atomicAdd(&sred[128 + cl], b2);
      }
    }
  }
  __syncthreads();

  #pragma unroll
  for (int pass = 0; pass < 8; ++pass) {
    int cidx = tid + pass * 256;          // 2048 chunks of 16B
    int r = cidx >> 4, kc = cidx & 15;
    int rr = row0 + r;
    if (rr < NN) {
      uint4 d = *(const uint4*)&u.c[r * 136 + kc * 8];
      *(uint4*)&Ch[(size_t)rr * N + col0 + kc * 8] = d;
    }
  }

  if (stats && tid < 128) {
    atomicAdd(&stats[col0 + tid], sred[tid]);
    atomicAdd(&stats[N + col0 + tid], sred[128 + tid]);
  }
}

// ------------------------------------------------------------------
// Slim BN stats over fp16 tensor (stride == F)
// ------------------------------------------------------------------
__global__ __launch_bounds__(256) void k_stats16(const _Float16* __restrict__ X, int F,
                                                 float* __restrict__ sums) {
  int tid = threadIdx.x;
  int npf = F >> 8;
  float s[2] = {0.f, 0.f}, s2[2] = {0.f, 0.f};
  for (int r = blockIdx.x; r < NN; r += gridDim.x) {
    #pragma unroll
    for (int i = 0; i < 2; ++i) {
      if (i < npf) {
        float v = (float)X[(size_t)r * F + tid + i * 256];
        s[i] += v; s2[i] += v * v;
      }
    }
  }
  #pragma unroll
  for (int i = 0; i < 2; ++i) {
    if (i < npf) {
      atomicAdd(&sums[tid + i * 256], s[i]);
      atomicAdd(&sums[F + tid + i * 256], s2[i]);
    }
  }
}

// ------------------------------------------------------------------
// L5 BN fold for pooling
// ------------------------------------------------------------------
__global__ __launch_bounds__(1024) void k_prep(const float* __restrict__ sums,
                                               const float* __restrict__ g5,
                                               const float* __restrict__ be5,
                                               const float* __restrict__ Wg,
                                               const float* __restrict__ bg,
                                               float* __restrict__ sc, float* __restrict__ sh,
                                               float* __restrict__ scWg, float* __restrict__ gconst) {
  __shared__ float red[1024];
  int f = threadIdx.x;
  const float inv_n = 1.f / NN;
  float mean = sums[f] * inv_n;
  float var  = sums[1024 + f] * inv_n - mean * mean;
  float s = g5[f] * rsqrtf(var + EPS_BN);
  float h = be5[f] - mean * s;
  sc[f] = s; sh[f] = h;
  float wgf = Wg[f];
  scWg[f] = s * wgf;
  red[f] = h * wgf;
  __syncthreads();
  for (int o = 512; o > 0; o >>= 1) {
    if (f < o) red[f] += red[f + o];
    __syncthreads();
  }
  if (f == 0) gconst[0] = red[0] + bg[0];
}

__global__ __launch_bounds__(256) void k_gate_aff(const _Float16* __restrict__ X,
                                                  const float* __restrict__ scWg,
                                                  const float* __restrict__ gconst,
                                                  float* __restrict__ gate) {
  __shared__ float red[256];
  int n = blockIdx.x, tid = threadIdx.x;
  int f = tid * 4;
  uint2 u = *(const uint2*)(X + (size_t)n * 1024 + f);
  half2v h0 = __builtin_bit_cast(half2v, u.x);
  half2v h1 = __builtin_bit_cast(half2v, u.y);
  float s = (float)h0[0] * scWg[f] + (float)h0[1] * scWg[f + 1]
          + (float)h1[0] * scWg[f + 2] + (float)h1[1] * scWg[f + 3];
  red[tid] = s;
  __syncthreads();
  for (int o = 128; o > 0; o >>= 1) {
    if (tid < o) red[tid] += red[tid + o];
    __syncthreads();
  }
  if (tid == 0) gate[n] = red[0] + gconst[0];
}

__global__ __launch_bounds__(64) void k_segred(const float* __restrict__ gate,
                                               const int* __restrict__ goff,
                                               float* __restrict__ gmax,
                                               float* __restrict__ gsum) {
  int g = blockIdx.x, tid = threadIdx.x;
  int beg = goff[g], end = goff[g + 1];
  float m = -3.4e38f;
  for (int n = beg + tid; n < end; n += 64) m = fmaxf(m, gate[n]);
  for (int o = 32; o > 0; o >>= 1) m = fmaxf(m, __shfl_down(m, o, 64));
  m = __shfl(m, 0, 64);
  float s = 0.f;
  for (int n = beg + tid; n < end; n += 64) s += expf(gate[n] - m);
  for (int o = 32; o > 0; o >>= 1) s += __shfl_down(s, o, 64);
  if (tid == 0) { gmax[g] = m; gsum[g] = s; }
}

__global__ __launch_bounds__(256) void k_pool_aff(const _Float16* __restrict__ X,
                                                  const float* __restrict__ gate,
                                                  const int* __restrict__ goff,
                                                  const float* __restrict__ gmax,
                                                  const float* __restrict__ gsum,
                                                  const float* __restrict__ sc,
                                                  const float* __restrict__ sh,
                                                  float* __restrict__ pooled) {
  int g = blockIdx.x, tid = threadIdx.x;
  int beg = goff[g], end = goff[g + 1];
  int f = tid * 4;
  float acc[4] = {0.f, 0.f, 0.f, 0.f};
  bool nonempty = end > beg;
  if (nonempty) {
    float m = gmax[g], inv = 1.f / gsum[g];
    for (int n = beg; n < end; ++n) {
      float a = expf(gate[n] - m) * inv;
      uint2 u = *(const uint2*)(X + (size_t)n * 1024 + f);
      half2v h0 = __builtin_bit_cast(half2v, u.x);
      half2v h1 = __builtin_bit_cast(half2v, u.y);
      acc[0] += a * (float)h0[0];
      acc[1] += a * (float)h0[1];
      acc[2] += a * (float)h1[0];
      acc[3] += a * (float)h1[1];
    }
  }
  #pragma unroll
  for (int i = 0; i < 4; ++i) {
    int ff = f + i;
    float v = nonempty ? (acc[i] * sc[ff] + sh[ff]) : 0.f;
    pooled[(size_t)g * 1024 + ff] = v;
  }
}

// ------------------------------------------------------------------
// MLP head
// ------------------------------------------------------------------
__global__ __launch_bounds__(128) void k_head(const float* __restrict__ pooled,
                                              const float* __restrict__ Wf2, const float* __restrict__ bf2,
                                              const float* __restrict__ Wf3, const float* __restrict__ bf3,
                                              const float* __restrict__ Wf4, const float* __restrict__ bf4,
                                              float* __restrict__ out) {
  __shared__ float sp[1024];
  __shared__ float sp2[128];
  __shared__ float sp3[16];
  int g = blockIdx.x, tid = threadIdx.x;
  #pragma unroll
  for (int i = 0; i < 8; ++i) sp[tid + i * 128] = pooled[(size_t)g * 1024 + tid + i * 128];
  __syncthreads();
  float s = bf2[tid];
  for (int k = 0; k < 1024; ++k) s += sp[k] * Wf2[k * 128 + tid];
  sp2[tid] = fmaxf(s, 0.f);
  __syncthreads();
  if (tid < 16) {
    float t = bf3[tid];
    for (int k = 0; k < 128; ++k) t += sp2[k] * Wf3[k * 16 + tid];
    sp3[tid] = fmaxf(t, 0.f);
  }
  __syncthreads();
  if (tid == 0) {
    float t = bf4[0];
    for (int k = 0; k < 16; ++k) t += sp3[k] * Wf4[k];
    out[g] = t;
  }
}

// ------------------------------------------------------------------
extern "C" void kernel_launch(void* const* d_in, const int* in_sizes, int n_in,
                              void* d_out, int out_size, void* d_ws, size_t ws_size,
                              hipStream_t stream) {
  const float* x     = (const float*)d_in[0];
  const int*   ei    = (const int*)d_in[1];
  const int*   batch = (const int*)d_in[2];
  const float* W[5]; const float* b[5]; const float* g[5]; const float* be[5];
  for (int l = 0; l < 5; ++l) {
    W[l]  = (const float*)d_in[3 + 4 * l];
    b[l]  = (const float*)d_in[4 + 4 * l];
    g[l]  = (const float*)d_in[5 + 4 * l];
    be[l] = (const float*)d_in[6 + 4 * l];
  }
  const float* Wg  = (const float*)d_in[23];
  const float* bg  = (const float*)d_in[24];
  const float* Wf2 = (const float*)d_in[25];
  const float* bf2 = (const float*)d_in[26];
  const float* Wf3 = (const float*)d_in[27];
  const float* bf3 = (const float*)d_in[28];
  const float* Wf4 = (const float*)d_in[29];
  const float* bf4 = (const float*)d_in[30];
  float* out = (float*)d_out;

  const int* row = ei;
  const int* col = ei + NE;

  char* base = (char*)d_ws;
  size_t off = 0;
  auto alloc = [&](size_t bytes) -> char* {
    char* p = base + off;
    off = (off + bytes + 255) & ~(size_t)255;
    return p;
  };
  _Float16*  AH  = (_Float16*)alloc((size_t)MPAD * 1024 * 2); // GEMM A operand / r2 / a4 / a5
  _Float16*  ASM = (_Float16*)alloc((size_t)MPAD * 32 * 2);   // L1 A operand
  _Float16*  BF  = (_Float16*)alloc((size_t)NN * 512 * 2);    // gather buffer
  _Float16*  BF2 = (_Float16*)alloc((size_t)NN * 512 * 2);    // gather buffer
  _Float16*  H5  = (_Float16*)alloc((size_t)NN * 1024 * 2);   // r5 fp16
  const int wtsz[5] = {1024 * 32, 512 * 1024, 256 * 512, 512 * 256, 1024 * 512};
  _Float16* WT[5];
  for (int l = 0; l < 5; ++l) WT[l] = (_Float16*)alloc((size_t)wtsz[l] * 2);
  float* c2  = (float*)alloc(512 * 4);
  float* c3  = (float*)alloc(256 * 4);
  float* dinv    = (float*)alloc(NN * 4);
  int*   indptr  = (int*)alloc((NN + 1) * 4);
  int*   cursor  = (int*)alloc(NN * 4);
  int2*  csw     = (int2*)alloc((size_t)NTOT * 8);
  int*   goff    = (int*)alloc((NG + 1) * 4);
  int*   gcur    = (int*)alloc(NG * 4);
  float* gate    = (float*)alloc(NN * 4);
  float* gmax    = (float*)alloc(NG * 4);
  float* gsum    = (float*)alloc(NG * 4);
  float* pooled  = (float*)alloc((size_t)NG * 1024 * 4);
  float* scv5 = (float*)alloc(1024 * 4);
  float* shv5 = (float*)alloc(1024 * 4);
  float* scWg = (float*)alloc(1024 * 4);
  float* gconst = (float*)alloc(4);
  // single zeroed region: bns(6656) | deg(NN) | gcnt(NG) | rsum(NN)
  size_t znf = 6656 + NN + NG + NN;
  float* zbase = (float*)alloc(znf * 4);
  float* bns  = zbase;
  int*   deg  = (int*)(zbase + 6656);
  int*   gcnt = (int*)(zbase + 6656 + NN);
  float* rsum = zbase + 6656 + NN + NG;
  float* bns1 = bns;          // F=1024
  float* bns2 = bns + 2048;   // F=512
  float* bns3 = bns + 3072;   // F=256
  float* bns4 = bns + 3584;   // F=512
  float* bns5 = bns + 4608;   // F=1024

  // ---- preprocessing ----
  hipMemsetAsync(zbase, 0, znf * 4, stream);
  k_deg<<<(NTOT + 255) / 256, 256, 0, stream>>>(col, deg, batch, gcnt);
  k_scan<<<1, 1024, 0, stream>>>(deg, NN, indptr, cursor, dinv);
  k_fill<<<(NTOT + 255) / 256, 256, 0, stream>>>(row, col, dinv, cursor, csw, rsum);
  k_scan<<<1, 1024, 0, stream>>>(gcnt, NG, goff, gcur, nullptr);
  k_wconv3<<<2688, 256, 0, stream>>>(W[0], W[3], W[4], WT[0], WT[3], WT[4]);

  auto gemm = [&](const _Float16* Aop, int wl, const float* bias,
                  _Float16* Ch, float* stats, int Nn, int Kk, int relu) {
    int nbx = Nn / 128;
    if (Kk == 32)
      k_gemm16<32><<<nbx * 160, 256, 0, stream>>>(Aop, WT[wl], bias, Ch, stats, Nn, Kk, relu, nbx);
    else
      k_gemm16<64><<<nbx * 160, 256, 0, stream>>>(Aop, WT[wl], bias, Ch, stats, Nn, Kk, relu, nbx);
  };

  // ---- layer 1 (29 -> 1024): agg-first; GEMM1 fuses bias/relu/stats ----
  k_agg29<<<NN, AGG_T, 0, stream>>>(x, indptr, csw, ASM);
  gemm(ASM, 0, b[0], AH, bns1, 1024, 32, 1);                     // r1 fp16

  // ---- layer 2 (1024 -> 512): BN1 folded into W2; transform-first ----
  k_wfold<<<512, 256, 0, stream>>>(W[1], 1024, 512, bns1, g[0], be[0], WT[1], c2);
  gemm(AH, 1, nullptr, BF, nullptr, 512, 1024, 0);               // G2
  k_aggv<8, 0><<<NN / 4, 256, 0, stream>>>(BF, AH, indptr, csw, rsum, c2, b[1], nullptr); // r2
  k_stats16<<<512, 256, 0, stream>>>(AH, 512, bns2);

  // ---- layer 3 (512 -> 256): BN2 folded into W3; transform-first ----
  k_wfold<<<256, 256, 0, stream>>>(W[2], 512, 256, bns2, g[1], be[1], WT[2], c3);
  gemm(AH, 2, nullptr, BF2, nullptr, 256, 512, 0);               // G3
  k_aggv<4, 0><<<NN / 4, 256, 0, stream>>>(BF2, BF, indptr, csw, rsum, c3, b[2], nullptr); // r3
  k_stats16<<<512, 256, 0, stream>>>(BF, 256, bns3);

  // ---- layer 4 (256 -> 512): agg-first, BN3 inline in agg epilogue ----
  k_aggv<4, 1><<<NN / 4, 256, 0, stream>>>(BF, AH, indptr, csw, rsum, bns3, g[2], be[2]); // a4
  gemm(AH, 3, b[3], BF2, bns4, 512, 256, 1);                     // r4 fp16 + stats

  // ---- layer 5 (512 -> 1024): agg-first, BN4 inline; GEMM5 fp16 out ----
  k_aggv<8, 1><<<NN / 4, 256, 0, stream>>>(BF2, AH, indptr, csw, rsum, bns4, g[3], be[3]); // a5
  gemm(AH, 4, b[4], H5, bns5, 1024, 512, 1);                     // r5 fp16 + stats

  // ---- attention pooling with folded BN5 affine ----
  k_prep<<<1, 1024, 0, stream>>>(bns5, g[4], be[4], Wg, bg, scv5, shv5, scWg, gconst);
  k_gate_aff<<<NN, 256, 0, stream>>>(H5, scWg, gconst, gate);
  k_segred<<<NG, 64, 0, stream>>>(gate, goff, gmax, gsum);
  k_pool_aff<<<NG, 256, 0, stream>>>(H5, gate, goff, gmax, gsum, scv5, shv5, pooled);

  // ---- MLP head ----
  k_head<<<NG, 128, 0, stream>>>(pooled, Wf2, bf2, Wf3, bf3, Wf4, bf4, out);
}